// Round 1
// baseline (419.866 us; speedup 1.0000x reference)
//
#include <hip/hip_runtime.h>
#include <stdint.h>

typedef unsigned short u16;
typedef __attribute__((ext_vector_type(8))) short bf16x8;
typedef __attribute__((ext_vector_type(4))) float f32x4;

#define SCALE 0.125f

__device__ __forceinline__ u16 f2bf(float f) {
  union { float f; unsigned u; } v; v.f = f;
  unsigned r = v.u + 0x7fffu + ((v.u >> 16) & 1u);
  return (u16)(r >> 16);
}
__device__ __forceinline__ float bf2f(u16 u) {
  union { unsigned u; float f; } v; v.u = ((unsigned)u) << 16;
  return v.f;
}

__device__ __forceinline__ void gload16(const void* g, void* l) {
  __builtin_amdgcn_global_load_lds(
      (const __attribute__((address_space(1))) unsigned int*)g,
      (__attribute__((address_space(3))) unsigned int*)l, 16, 0, 0);
}

__global__ void cvt_f32_bf16(const float4* __restrict__ s, uint2* __restrict__ d, int n4) {
  int i = blockIdx.x * blockDim.x + threadIdx.x;
  int stride = gridDim.x * blockDim.x;
  for (; i < n4; i += stride) {
    float4 v = s[i];
    uint2 o;
    o.x = (unsigned)f2bf(v.x) | ((unsigned)f2bf(v.y) << 16);
    o.y = (unsigned)f2bf(v.z) | ((unsigned)f2bf(v.w) << 16);
    d[i] = o;
  }
}

// C = A @ B^T, A [M,768] bf16, B [N,768] bf16, 128x128 tile, 4 waves.
// MODE 0: bf16 C store, ldc given.
// MODE 1: vT+cb store (A rows: 0-767 -> vT bf16 +bias, 768-779 -> cb f32, else skip)
// MODE 2: f32 C store + bias[col], ldc given.
template <int MODE>
__global__ __launch_bounds__(256, 2) void gemm_bt(
    const u16* __restrict__ A, const u16* __restrict__ Bm,
    void* __restrict__ Cp, void* __restrict__ Cp2,
    const float* __restrict__ bias, int ldc) {
  __shared__ u16 Ab[128 * 32];
  __shared__ u16 Bb[128 * 32];
  const int tid = threadIdx.x;
  const int l = tid & 63, w = tid >> 6;
  const int g = l >> 4, l15 = l & 15;
  const int wr = w >> 1, wc = w & 1;
  const int rowbase = blockIdx.y * 128, colbase = blockIdx.x * 128;

  f32x4 acc[4][4] = {};
  const char* Abase = (const char*)A + (size_t)rowbase * 1536;
  const char* Bbase = (const char*)Bm + (size_t)colbase * 1536;

  for (int kk = 0; kk < 768; kk += 32) {
    __syncthreads();
#pragma unroll
    for (int p = 0; p < 2; ++p) {
      int o = p * 4096 + w * 1024 + l * 16;
      int row = o >> 6, cb = o & 63;
      gload16(Abase + (size_t)row * 1536 + kk * 2 + cb, &Ab[(p * 4096 + w * 1024) / 2]);
      gload16(Bbase + (size_t)row * 1536 + kk * 2 + cb, &Bb[(p * 4096 + w * 1024) / 2]);
    }
    __syncthreads();
    bf16x8 af[4], bfr[4];
#pragma unroll
    for (int i = 0; i < 4; ++i) {
      af[i] = *(const bf16x8*)&Ab[(wr * 64 + i * 16 + l15) * 32 + g * 8];
      bfr[i] = *(const bf16x8*)&Bb[(wc * 64 + i * 16 + l15) * 32 + g * 8];
    }
#pragma unroll
    for (int mi = 0; mi < 4; ++mi)
#pragma unroll
      for (int ni = 0; ni < 4; ++ni)
        acc[mi][ni] = __builtin_amdgcn_mfma_f32_16x16x32_bf16(af[mi], bfr[ni], acc[mi][ni], 0, 0, 0);
  }

#pragma unroll
  for (int mi = 0; mi < 4; ++mi)
#pragma unroll
    for (int ni = 0; ni < 4; ++ni)
#pragma unroll
      for (int r = 0; r < 4; ++r) {
        int row = rowbase + wr * 64 + mi * 16 + g * 4 + r;
        int col = colbase + wc * 64 + ni * 16 + l15;
        float v = acc[mi][ni][r];
        if (MODE == 0) {
          ((u16*)Cp)[(size_t)row * ldc + col] = f2bf(v);
        } else if (MODE == 2) {
          ((float*)Cp)[(size_t)row * ldc + col] = v + bias[col];
        } else {
          int b = col >> 10, nn = col & 1023;
          if (row < 768) {
            ((u16*)Cp)[(size_t)b * 786432 + (size_t)row * 1024 + nn] = f2bf(v + bias[row]);
          } else if (row < 780) {
            ((float*)Cp2)[(size_t)b * 12288 + (size_t)(row - 768) * 1024 + nn] = v;
          }
        }
      }
}

// Flash attention. grid = (b=8, h=12, qb=16), 256 threads (4 waves x 16 q-rows).
__global__ __launch_bounds__(256, 2) void attn_kernel(
    const u16* __restrict__ QK,   // [B*N][1536] bf16 (cols 0-767 q_shared, 768-1535 k)
    const u16* __restrict__ vT,   // [B][768][1024] bf16
    const float* __restrict__ cb, // [B][12][1024]
    const float* __restrict__ Wmix,
    u16* __restrict__ OH)         // [B*N][768] bf16
{
  __shared__ u16 Kb[64 * 128];
  __shared__ u16 Vb[64 * 64];
  __shared__ u16 Pb[4 * 16 * 64];
  const int b = blockIdx.x, h = blockIdx.y, qb = blockIdx.z;
  const int tid = threadIdx.x;
  const int l = tid & 63, w = tid >> 6;
  const int g = l >> 4, l15 = l & 15;

  const size_t qkbase = (size_t)b * 1024 * 1536;

  // ---- phase 1: Q*Wmix fragments into registers
  bf16x8 qreg[24];
  {
    const char* Qsrc = (const char*)QK + (qkbase + (size_t)qb * 64 * 1536) * 2;
#pragma unroll
    for (int dc = 0; dc < 6; ++dc) {
      __syncthreads();
#pragma unroll
      for (int p = 0; p < 4; ++p) {
        int o = p * 4096 + w * 1024 + l * 16;
        int row = o >> 8;
        int ch = (o >> 4) & 15;
        int sch = ch ^ (row & 7);
        gload16(Qsrc + (size_t)row * 3072 + dc * 256 + sch * 16, &Kb[(p * 4096 + w * 1024) / 2]);
      }
      __syncthreads();
#pragma unroll
      for (int ds = 0; ds < 4; ++ds) {
        int row = w * 16 + l15;
        int ch = (ds * 4 + g) ^ (row & 7);
        bf16x8 qv = *(const bf16x8*)&Kb[row * 128 + ch * 8];
        const float* wm = Wmix + h * 768 + dc * 128 + ds * 32 + g * 8;
        bf16x8 qh;
#pragma unroll
        for (int j = 0; j < 8; ++j) {
          float f = bf2f((u16)qv[j]) * wm[j];
          qh[j] = (short)f2bf(f);
        }
        qreg[dc * 4 + ds] = qh;
      }
    }
  }

  float mrow[4], lrow[4];
#pragma unroll
  for (int r = 0; r < 4; ++r) { mrow[r] = -INFINITY; lrow[r] = 0.f; }
  f32x4 oacc[4] = {};

  const char* Ksrc = (const char*)QK + qkbase * 2 + 768 * 2;
  const char* Vsrc = (const char*)vT + (size_t)(b * 12 + h) * 64 * 1024 * 2;
  const float* cbp = cb + (size_t)(b * 12 + h) * 1024;

  for (int kt = 0; kt < 16; ++kt) {
    f32x4 s[4] = {};
#pragma unroll
    for (int dc = 0; dc < 6; ++dc) {
      __syncthreads();
#pragma unroll
      for (int p = 0; p < 4; ++p) {
        int o = p * 4096 + w * 1024 + l * 16;
        int row = o >> 8;
        int ch = (o >> 4) & 15;
        int sch = ch ^ (row & 7);
        gload16(Ksrc + (size_t)(kt * 64 + row) * 3072 + dc * 256 + sch * 16,
                &Kb[(p * 4096 + w * 1024) / 2]);
      }
      if (dc == 0) {
#pragma unroll
        for (int p = 0; p < 2; ++p) {
          int o = p * 4096 + w * 1024 + l * 16;
          int row = o >> 7;
          int ch = (o >> 4) & 7;
          int sch = ch ^ (row & 7);
          gload16(Vsrc + (size_t)row * 2048 + kt * 128 + sch * 16,
                  &Vb[(p * 4096 + w * 1024) / 2]);
        }
      }
      __syncthreads();
#pragma unroll
      for (int ds = 0; ds < 4; ++ds) {
        bf16x8 kf[4];
#pragma unroll
        for (int cf = 0; cf < 4; ++cf) {
          int row = cf * 16 + l15;
          int ch = (ds * 4 + g) ^ (row & 7);
          kf[cf] = *(const bf16x8*)&Kb[row * 128 + ch * 8];
        }
#pragma unroll
        for (int cf = 0; cf < 4; ++cf)
          s[cf] = __builtin_amdgcn_mfma_f32_16x16x32_bf16(qreg[dc * 4 + ds], kf[cf], s[cf], 0, 0, 0);
      }
    }

    // online softmax
    float cbv[4];
#pragma unroll
    for (int cf = 0; cf < 4; ++cf) cbv[cf] = cbp[kt * 64 + cf * 16 + l15];
    float z[4][4];
#pragma unroll
    for (int cf = 0; cf < 4; ++cf)
#pragma unroll
      for (int r = 0; r < 4; ++r) z[cf][r] = (s[cf][r] + cbv[cf]) * SCALE;

#pragma unroll
    for (int r = 0; r < 4; ++r) {
      float mx = fmaxf(fmaxf(z[0][r], z[1][r]), fmaxf(z[2][r], z[3][r]));
      mx = fmaxf(mx, __shfl_xor(mx, 1));
      mx = fmaxf(mx, __shfl_xor(mx, 2));
      mx = fmaxf(mx, __shfl_xor(mx, 4));
      mx = fmaxf(mx, __shfl_xor(mx, 8));
      float mnew = fmaxf(mrow[r], mx);
      float alpha = __expf(mrow[r] - mnew);
      mrow[r] = mnew;
      float rs = 0.f;
#pragma unroll
      for (int cf = 0; cf < 4; ++cf) {
        float p = __expf(z[cf][r] - mnew);
        z[cf][r] = p;
        rs += p;
      }
      rs += __shfl_xor(rs, 1);
      rs += __shfl_xor(rs, 2);
      rs += __shfl_xor(rs, 4);
      rs += __shfl_xor(rs, 8);
      lrow[r] = lrow[r] * alpha + rs;
#pragma unroll
      for (int vf = 0; vf < 4; ++vf) oacc[vf][r] *= alpha;
    }

    // write P (bf16) to per-wave LDS, swizzled
#pragma unroll
    for (int cf = 0; cf < 4; ++cf)
#pragma unroll
      for (int r = 0; r < 4; ++r) {
        int row = g * 4 + r;
        int colb = (cf * 16 + l15) * 2;
        int byte = (((colb >> 4) ^ (row & 7)) << 4) | (colb & 15);
        Pb[(w * 2048 + row * 128 + byte) >> 1] = f2bf(z[cf][r]);
      }

    // PV
#pragma unroll
    for (int kk = 0; kk < 2; ++kk) {
      int pch = (kk * 4 + g) ^ (l15 & 7);
      bf16x8 pa = *(const bf16x8*)&Pb[(w * 2048 + l15 * 128 + pch * 16) >> 1];
#pragma unroll
      for (int vf = 0; vf < 4; ++vf) {
        int vrow = vf * 16 + l15;
        int vch = (kk * 4 + g) ^ (vrow & 7);
        bf16x8 vb = *(const bf16x8*)&Vb[(vrow * 128 + vch * 16) >> 1];
        oacc[vf] = __builtin_amdgcn_mfma_f32_16x16x32_bf16(pa, vb, oacc[vf], 0, 0, 0);
      }
    }
  }

  // epilogue
#pragma unroll
  for (int vf = 0; vf < 4; ++vf)
#pragma unroll
    for (int r = 0; r < 4; ++r) {
      int n = qb * 64 + w * 16 + g * 4 + r;
      int col = h * 64 + vf * 16 + l15;
      float v = oacc[vf][r] / lrow[r];
      OH[((size_t)b * 1024 + n) * 768 + col] = f2bf(v);
    }
}

static inline int cvtblocks(int n4) {
  int nb = (n4 + 255) / 256;
  return nb > 2048 ? 2048 : nb;
}

extern "C" void kernel_launch(void* const* d_in, const int* in_sizes, int n_in,
                              void* d_out, int out_size, void* d_ws, size_t ws_size,
                              hipStream_t stream) {
  (void)in_sizes; (void)n_in; (void)out_size; (void)ws_size;
  const float* x = (const float*)d_in[0];
  const float* Wq = (const float*)d_in[1];
  const float* Wk = (const float*)d_in[2];
  const float* Wv = (const float*)d_in[3];
  const float* bv = (const float*)d_in[4];
  const float* Wmix = (const float*)d_in[5];
  const float* Wcb = (const float*)d_in[6];
  const float* Wproj = (const float*)d_in[7];
  const float* bproj = (const float*)d_in[8];
  float* out = (float*)d_out;

  char* ws = (char*)d_ws;
  u16* xbf = (u16*)(ws);                 // 12582912 B
  u16* Wqk = (u16*)(ws + 12582912);      // 2359296 B
  u16* Wvcb = (u16*)(ws + 14942208);     // 1376256 B (896x768, rows >=780 unused)
  u16* Wpj = (u16*)(ws + 16318464);      // 1179648 B
  u16* QKb = (u16*)(ws + 17498112);      // 25165824 B
  u16* vT = (u16*)(ws + 42663936);       // 12582912 B
  float* cbb = (float*)(ws + 55246848);  // 393216 B
  u16* OH = (u16*)(ws + 55640064);       // 12582912 B  (end 68222976)

  cvt_f32_bf16<<<cvtblocks(1572864), 256, 0, stream>>>((const float4*)x, (uint2*)xbf, 1572864);
  cvt_f32_bf16<<<cvtblocks(147456), 256, 0, stream>>>((const float4*)Wq, (uint2*)Wqk, 147456);
  cvt_f32_bf16<<<cvtblocks(147456), 256, 0, stream>>>((const float4*)Wk, (uint2*)(Wqk + 589824), 147456);
  cvt_f32_bf16<<<cvtblocks(147456), 256, 0, stream>>>((const float4*)Wv, (uint2*)Wvcb, 147456);
  cvt_f32_bf16<<<cvtblocks(2304), 256, 0, stream>>>((const float4*)Wcb, (uint2*)(Wvcb + 589824), 2304);
  cvt_f32_bf16<<<cvtblocks(147456), 256, 0, stream>>>((const float4*)Wproj, (uint2*)Wpj, 147456);

  gemm_bt<0><<<dim3(12, 64), 256, 0, stream>>>(xbf, Wqk, QKb, nullptr, nullptr, 1536);
  gemm_bt<1><<<dim3(64, 7), 256, 0, stream>>>(Wvcb, xbf, vT, cbb, bv, 0);
  attn_kernel<<<dim3(8, 12, 16), 256, 0, stream>>>(QKb, vT, cbb, Wmix, OH);
  gemm_bt<2><<<dim3(6, 64), 256, 0, stream>>>(OH, Wpj, out, nullptr, bproj, 768);
}

// Round 2
// 371.306 us; speedup vs baseline: 1.1308x; 1.1308x over previous
//
#include <hip/hip_runtime.h>
#include <stdint.h>

typedef unsigned short u16;
typedef __attribute__((ext_vector_type(8))) short bf16x8;
typedef __attribute__((ext_vector_type(4))) float f32x4;

#define KLOG2E 0.18033688011112043f  // SCALE(0.125) * log2(e)

__device__ __forceinline__ u16 f2bf(float f) {
  union { float f; unsigned u; } v; v.f = f;
  unsigned r = v.u + 0x7fffu + ((v.u >> 16) & 1u);
  return (u16)(r >> 16);
}
__device__ __forceinline__ float bf2f(u16 u) {
  union { unsigned u; float f; } v; v.u = ((unsigned)u) << 16;
  return v.f;
}

__device__ __forceinline__ void gload16(const void* g, void* l) {
  __builtin_amdgcn_global_load_lds(
      (const __attribute__((address_space(1))) unsigned int*)g,
      (__attribute__((address_space(3))) unsigned int*)l, 16, 0, 0);
}

__global__ void cvt_f32_bf16(const float4* __restrict__ s, uint2* __restrict__ d, int n4) {
  int i = blockIdx.x * blockDim.x + threadIdx.x;
  int stride = gridDim.x * blockDim.x;
  for (; i < n4; i += stride) {
    float4 v = s[i];
    uint2 o;
    o.x = (unsigned)f2bf(v.x) | ((unsigned)f2bf(v.y) << 16);
    o.y = (unsigned)f2bf(v.z) | ((unsigned)f2bf(v.w) << 16);
    d[i] = o;
  }
}

// C = A @ B^T, A [M,768] bf16, B [N,768] bf16, 128x128 tile, 4 waves.
// MODE 0: bf16 C store, ldc given.
// MODE 1: vT+cb store (A rows: 0-767 -> vT bf16 +bias, 768-779 -> cb f32 pre-scaled)
// MODE 2: f32 C store + bias[col], ldc given.
template <int MODE>
__global__ __launch_bounds__(256, 2) void gemm_bt(
    const u16* __restrict__ A, const u16* __restrict__ Bm,
    void* __restrict__ Cp, void* __restrict__ Cp2,
    const float* __restrict__ bias, int ldc) {
  __shared__ u16 Ab[128 * 32];
  __shared__ u16 Bb[128 * 32];
  const int tid = threadIdx.x;
  const int l = tid & 63, w = tid >> 6;
  const int g = l >> 4, l15 = l & 15;
  const int wr = w >> 1, wc = w & 1;
  const int rowbase = blockIdx.y * 128, colbase = blockIdx.x * 128;

  f32x4 acc[4][4] = {};
  const char* Abase = (const char*)A + (size_t)rowbase * 1536;
  const char* Bbase = (const char*)Bm + (size_t)colbase * 1536;

  for (int kk = 0; kk < 768; kk += 32) {
    __syncthreads();
#pragma unroll
    for (int p = 0; p < 2; ++p) {
      int o = p * 4096 + w * 1024 + l * 16;
      int row = o >> 6, cb = o & 63;
      gload16(Abase + (size_t)row * 1536 + kk * 2 + cb, &Ab[(p * 4096 + w * 1024) / 2]);
      gload16(Bbase + (size_t)row * 1536 + kk * 2 + cb, &Bb[(p * 4096 + w * 1024) / 2]);
    }
    __syncthreads();
    bf16x8 af[4], bfr[4];
#pragma unroll
    for (int i = 0; i < 4; ++i) {
      af[i] = *(const bf16x8*)&Ab[(wr * 64 + i * 16 + l15) * 32 + g * 8];
      bfr[i] = *(const bf16x8*)&Bb[(wc * 64 + i * 16 + l15) * 32 + g * 8];
    }
#pragma unroll
    for (int mi = 0; mi < 4; ++mi)
#pragma unroll
      for (int ni = 0; ni < 4; ++ni)
        acc[mi][ni] = __builtin_amdgcn_mfma_f32_16x16x32_bf16(af[mi], bfr[ni], acc[mi][ni], 0, 0, 0);
  }

#pragma unroll
  for (int mi = 0; mi < 4; ++mi)
#pragma unroll
    for (int ni = 0; ni < 4; ++ni)
#pragma unroll
      for (int r = 0; r < 4; ++r) {
        int row = rowbase + wr * 64 + mi * 16 + g * 4 + r;
        int col = colbase + wc * 64 + ni * 16 + l15;
        float v = acc[mi][ni][r];
        if (MODE == 0) {
          ((u16*)Cp)[(size_t)row * ldc + col] = f2bf(v);
        } else if (MODE == 2) {
          ((float*)Cp)[(size_t)row * ldc + col] = v + bias[col];
        } else {
          int b = col >> 10, nn = col & 1023;
          if (row < 768) {
            ((u16*)Cp)[(size_t)b * 786432 + (size_t)row * 1024 + nn] = f2bf(v + bias[row]);
          } else if (row < 780) {
            ((float*)Cp2)[(size_t)b * 12288 + (size_t)(row - 768) * 1024 + nn] = v * KLOG2E;
          }
        }
      }
}

// Flash attention v2: swapped QK^T (K as A operand -> per-lane softmax),
// K/V double-buffered, exp2 softmax, b64 P path.
// grid = (b=8, h=12, qb=16), 256 threads (4 waves x 16 q-rows each).
__global__ __launch_bounds__(256, 2) void attn2(
    const u16* __restrict__ QK,   // [B*N][1536] bf16 (cols 0-767 q_shared, 768-1535 k)
    const u16* __restrict__ vT,   // [B][768][1024] bf16
    const float* __restrict__ cb, // [B][12][1024], pre-scaled by KLOG2E
    const float* __restrict__ Wmix,
    u16* __restrict__ OH)         // [B*N][768] bf16
{
  __shared__ u16 Kb[2][8192];   // 2 x 16KB: 64 rows x 256B, 16B-slot XOR swizzle
  __shared__ u16 Vb[2][4096];   // 2 x 8KB: 64 d-rows x 128B
  __shared__ u16 Pb[4][1024];   // per-wave: 16 q-rows x 128B
  const int b = blockIdx.x, h = blockIdx.y, qb = blockIdx.z;
  const int tid = threadIdx.x;
  const int l = tid & 63, w = tid >> 6;
  const int g = l >> 4, l15 = l & 15;

  const char* Qsrc = (const char*)QK + ((size_t)b * 1024 + qb * 64) * 3072;
  const char* Ksrc = (const char*)QK + (size_t)b * 1024 * 3072 + 1536;
  const char* Vsrc = (const char*)vT + (size_t)(b * 12 + h) * 131072;
  const float* cbp = cb + (size_t)(b * 12 + h) * 1024;

  // ---- Q prologue: stage 64 q-rows per 128-dim chunk, multiply by Wmix*KLOG2E
  bf16x8 qreg[24];
#pragma unroll
  for (int dc = 0; dc < 6; ++dc) {
    __syncthreads();
#pragma unroll
    for (int p = 0; p < 4; ++p) {
      int o = p * 4096 + w * 1024 + l * 16;
      int row = o >> 8, ch = (o >> 4) & 15;
      gload16(Qsrc + (size_t)row * 3072 + dc * 256 + ((ch ^ (row & 7)) * 16),
              (char*)Kb[0] + p * 4096 + w * 1024);
    }
    __syncthreads();
#pragma unroll
    for (int ds = 0; ds < 4; ++ds) {
      int row = w * 16 + l15;
      int ch = (ds * 4 + g) ^ (row & 7);
      bf16x8 qv = *(const bf16x8*)((const char*)Kb[0] + row * 256 + ch * 16);
      const float* wm = Wmix + h * 768 + dc * 128 + ds * 32 + g * 8;
      bf16x8 qh;
#pragma unroll
      for (int j = 0; j < 8; ++j)
        qh[j] = (short)f2bf(bf2f((u16)qv[j]) * (wm[j] * KLOG2E));
      qreg[dc * 4 + ds] = qh;
    }
  }
  __syncthreads();

  auto STK = [&](int kt, int dc, int buf) {
#pragma unroll
    for (int p = 0; p < 4; ++p) {
      int o = p * 4096 + w * 1024 + l * 16;
      int row = o >> 8, ch = (o >> 4) & 15;
      gload16(Ksrc + (size_t)(kt * 64 + row) * 3072 + dc * 256 + ((ch ^ (row & 7)) * 16),
              (char*)Kb[buf] + p * 4096 + w * 1024);
    }
  };
  auto STV = [&](int kt, int buf) {
#pragma unroll
    for (int p = 0; p < 2; ++p) {
      int o = p * 4096 + w * 1024 + l * 16;
      int row = o >> 7, ch = (o >> 4) & 7;
      gload16(Vsrc + (size_t)row * 2048 + kt * 128 + ((ch ^ (row & 7)) * 16),
              (char*)Vb[buf] + p * 4096 + w * 1024);
    }
  };

  float mrow = -1e30f, lpart = 0.f;
  f32x4 oacc[4] = {};
  STK(0, 0, 0);
  STV(0, 0);
  __syncthreads();
  int cur = 0, vcur = 0;

  for (int kt = 0; kt < 16; ++kt) {
    f32x4 s[4] = {};
#pragma unroll
    for (int dc = 0; dc < 6; ++dc) {
      if (dc < 5) STK(kt, dc + 1, cur ^ 1);
      else if (kt < 15) STK(kt + 1, 0, cur ^ 1);
      if (dc == 1 && kt < 15) STV(kt + 1, vcur ^ 1);
#pragma unroll
      for (int ds = 0; ds < 4; ++ds) {
        bf16x8 kf[4];
#pragma unroll
        for (int cf = 0; cf < 4; ++cf) {
          int row = cf * 16 + l15;
          int ch = (ds * 4 + g) ^ (row & 7);
          kf[cf] = *(const bf16x8*)((const char*)Kb[cur] + row * 256 + ch * 16);
        }
#pragma unroll
        for (int cf = 0; cf < 4; ++cf)
          s[cf] = __builtin_amdgcn_mfma_f32_16x16x32_bf16(kf[cf], qreg[dc * 4 + ds], s[cf], 0, 0, 0);
      }
      __syncthreads();
      cur ^= 1;
    }

    // online softmax, per-lane: lane (g,l15) holds S[k=kt*64+cf*16+g*4+r][q=l15]
    float pmax = -1e30f;
#pragma unroll
    for (int cf = 0; cf < 4; ++cf) {
      float4 cbv = *(const float4*)(cbp + kt * 64 + cf * 16 + g * 4);
      s[cf][0] += cbv.x; s[cf][1] += cbv.y; s[cf][2] += cbv.z; s[cf][3] += cbv.w;
#pragma unroll
      for (int r = 0; r < 4; ++r) pmax = fmaxf(pmax, s[cf][r]);
    }
    pmax = fmaxf(pmax, __shfl_xor(pmax, 16));
    pmax = fmaxf(pmax, __shfl_xor(pmax, 32));
    float mold = mrow;
    float mnew = fmaxf(mold, pmax);
    mrow = mnew;
    float rs = 0.f;
#pragma unroll
    for (int cf = 0; cf < 4; ++cf)
#pragma unroll
      for (int r = 0; r < 4; ++r) {
        float p = exp2f(s[cf][r] - mnew);
        s[cf][r] = p;
        rs += p;
      }
    if (__ballot(pmax > mold)) {
      float alpha = exp2f(mold - mnew);
      lpart = lpart * alpha + rs;
      float a4[4];
#pragma unroll
      for (int r = 0; r < 4; ++r) a4[r] = __shfl(alpha, (l & 48) | (g * 4 + r));
#pragma unroll
      for (int vf = 0; vf < 4; ++vf)
#pragma unroll
        for (int r = 0; r < 4; ++r) oacc[vf][r] *= a4[r];
    } else {
      lpart += rs;
    }

    // P pack (bf16 pairs) -> per-wave LDS, b64 writes, 16B-slot swizzle
#pragma unroll
    for (int cf = 0; cf < 4; ++cf) {
      unsigned u0 = (unsigned)f2bf(s[cf][0]) | ((unsigned)f2bf(s[cf][1]) << 16);
      unsigned u1 = (unsigned)f2bf(s[cf][2]) | ((unsigned)f2bf(s[cf][3]) << 16);
      int t = (cf * 2 + (g >> 1)) ^ (l15 & 7);
      uint2 uu; uu.x = u0; uu.y = u1;
      *(uint2*)((char*)Pb[w] + l15 * 128 + t * 16 + (g & 1) * 8) = uu;
    }

    // PV
#pragma unroll
    for (int kk = 0; kk < 2; ++kk) {
      int t = (kk * 4 + g) ^ (l15 & 7);
      bf16x8 pa = *(const bf16x8*)((const char*)Pb[w] + l15 * 128 + t * 16);
#pragma unroll
      for (int vf = 0; vf < 4; ++vf) {
        int vrow = vf * 16 + l15;
        int vch = (kk * 4 + g) ^ (vrow & 7);
        bf16x8 vv = *(const bf16x8*)((const char*)Vb[vcur] + vrow * 128 + vch * 16);
        oacc[vf] = __builtin_amdgcn_mfma_f32_16x16x32_bf16(pa, vv, oacc[vf], 0, 0, 0);
      }
    }
    vcur ^= 1;
  }

  // epilogue: reduce l across g-groups, divide, store
  float lfull = lpart;
  lfull += __shfl_xor(lfull, 16);
  lfull += __shfl_xor(lfull, 32);
  float lq[4];
#pragma unroll
  for (int r = 0; r < 4; ++r) lq[r] = __shfl(lfull, (l & 48) | (g * 4 + r));
#pragma unroll
  for (int vf = 0; vf < 4; ++vf)
#pragma unroll
    for (int r = 0; r < 4; ++r) {
      int n = qb * 64 + w * 16 + g * 4 + r;
      int col = h * 64 + vf * 16 + l15;
      OH[((size_t)b * 1024 + n) * 768 + col] = f2bf(oacc[vf][r] / lq[r]);
    }
}

static inline int cvtblocks(int n4) {
  int nb = (n4 + 255) / 256;
  return nb > 2048 ? 2048 : nb;
}

extern "C" void kernel_launch(void* const* d_in, const int* in_sizes, int n_in,
                              void* d_out, int out_size, void* d_ws, size_t ws_size,
                              hipStream_t stream) {
  (void)in_sizes; (void)n_in; (void)out_size; (void)ws_size;
  const float* x = (const float*)d_in[0];
  const float* Wq = (const float*)d_in[1];
  const float* Wk = (const float*)d_in[2];
  const float* Wv = (const float*)d_in[3];
  const float* bv = (const float*)d_in[4];
  const float* Wmix = (const float*)d_in[5];
  const float* Wcb = (const float*)d_in[6];
  const float* Wproj = (const float*)d_in[7];
  const float* bproj = (const float*)d_in[8];
  float* out = (float*)d_out;

  char* ws = (char*)d_ws;
  u16* xbf = (u16*)(ws);                 // 12582912 B
  u16* Wqk = (u16*)(ws + 12582912);      // 2359296 B
  u16* Wvcb = (u16*)(ws + 14942208);     // 1376256 B (896x768, rows >=780 unused)
  u16* Wpj = (u16*)(ws + 16318464);      // 1179648 B
  u16* QKb = (u16*)(ws + 17498112);      // 25165824 B
  u16* vT = (u16*)(ws + 42663936);       // 12582912 B
  float* cbb = (float*)(ws + 55246848);  // 393216 B
  u16* OH = (u16*)(ws + 55640064);       // 12582912 B  (end 68222976)

  cvt_f32_bf16<<<cvtblocks(1572864), 256, 0, stream>>>((const float4*)x, (uint2*)xbf, 1572864);
  cvt_f32_bf16<<<cvtblocks(147456), 256, 0, stream>>>((const float4*)Wq, (uint2*)Wqk, 147456);
  cvt_f32_bf16<<<cvtblocks(147456), 256, 0, stream>>>((const float4*)Wk, (uint2*)(Wqk + 589824), 147456);
  cvt_f32_bf16<<<cvtblocks(147456), 256, 0, stream>>>((const float4*)Wv, (uint2*)Wvcb, 147456);
  cvt_f32_bf16<<<cvtblocks(2304), 256, 0, stream>>>((const float4*)Wcb, (uint2*)(Wvcb + 589824), 2304);
  cvt_f32_bf16<<<cvtblocks(147456), 256, 0, stream>>>((const float4*)Wproj, (uint2*)Wpj, 147456);

  gemm_bt<0><<<dim3(12, 64), 256, 0, stream>>>(xbf, Wqk, QKb, nullptr, nullptr, 1536);
  gemm_bt<1><<<dim3(64, 7), 256, 0, stream>>>(Wvcb, xbf, vT, cbb, bv, 0);
  attn2<<<dim3(8, 12, 16), 256, 0, stream>>>(QKb, vT, cbb, Wmix, OH);
  gemm_bt<2><<<dim3(6, 64), 256, 0, stream>>>(OH, Wpj, out, nullptr, bproj, 768);
}